// Round 4
// baseline (518.683 us; speedup 1.0000x reference)
//
#include <hip/hip_runtime.h>
#include <hip/hip_bf16.h>

// Dense MHA per head: B=2, T=2048, K=2048, H=16, D=128. Inputs/outputs FP32
// (verified round 2: clamp signature ~1e4 in fp32 readback). MFMA compute in
// bf16 (RNE converts), softmax in fp32.
// 1 block = 4 waves = 64 q-rows of one (b,h); BN=64 keys/iter.
// K and V tiles staged fp32->bf16 into LDS once per block per tile:
//   Kt[key][d] rows padded to 136 bf16 (2-way banks max)
//   Vt transposed with XOR-granule swizzle (balanced banks both directions)
// P relayout C->A via per-wave LDS slice (stride 72, 16B-aligned b128 reads).

#define T_   2048
#define KLEN 2048
#define H_   16
#define D_   128
#define BN   64

typedef unsigned short u16;
typedef short bf16x8 __attribute__((ext_vector_type(8), may_alias));
typedef float f32x4 __attribute__((ext_vector_type(4)));
typedef float f32x8 __attribute__((ext_vector_type(8), may_alias));
typedef unsigned int u32a __attribute__((may_alias));
typedef u16 u16a __attribute__((may_alias));

__device__ __forceinline__ u16 f2bf(float f) {
    unsigned int u = __builtin_bit_cast(unsigned int, f);
    u += 0x7fffu + ((u >> 16) & 1u);   // RNE
    return (u16)(u >> 16);
}
__device__ __forceinline__ unsigned int pk2(float a, float b) {
    // low u16 = bf16(a), high u16 = bf16(b); integer RNE (no HIP struct:
    // __hip_bfloat162 is not trivially copyable on this ROCm -> no bit_cast)
    return (unsigned int)f2bf(a) | ((unsigned int)f2bf(b) << 16);
}

#define VT_BYTES 16384            /* 128 d-rows x 8 granules x 16B  */
#define KT_BYTES (64 * 136 * 2)   /* 17408: 64 keys x 136 bf16      */
#define PW_BYTES 2304             /* per wave: 16 x 72 bf16         */

__global__ __launch_bounds__(256, 2)
void gqa_fa_kernel(const float* __restrict__ q_g, const float* __restrict__ k_g,
                   const float* __restrict__ v_g, float* __restrict__ o_g) {
    __shared__ __align__(16) unsigned char smem[VT_BYTES + KT_BYTES + 4 * PW_BYTES];
    unsigned char* VtB = smem;
    unsigned char* KtB = smem + VT_BYTES;

    const int lane = threadIdx.x & 63;
    const int wave = threadIdx.x >> 6;
    const int c    = lane & 15;     // MFMA col lane / A-row lane
    const int quad = lane >> 4;

    const int qt = blockIdx.x & 31;        // 32 q-tiles
    const int bh = blockIdx.x >> 5;
    const int h  = bh & 15;
    const int b  = bh >> 4;

    const int q0 = qt * 64 + wave * 16;

    // ---- Q fragments (A layout): lane holds Q[q0+c][dc*32 + quad*8 + j]
    bf16x8 qf[4];
    {
        const float* qbase = q_g + (size_t)(b * T_ + q0 + c) * (H_ * D_) + h * D_ + quad * 8;
        #pragma unroll
        for (int dc = 0; dc < 4; ++dc) {
            f32x8 qv = *(const f32x8*)(qbase + dc * 32);
            uint4 w;
            w.x = pk2(qv[0], qv[1]); w.y = pk2(qv[2], qv[3]);
            w.z = pk2(qv[4], qv[5]); w.w = pk2(qv[6], qv[7]);
            qf[dc] = __builtin_bit_cast(bf16x8, w);
        }
    }

    f32x4 acc_o[8];
    #pragma unroll
    for (int dt = 0; dt < 8; ++dt) acc_o[dt] = (f32x4){0.f, 0.f, 0.f, 0.f};
    float m_i[4], l_i[4];
    #pragma unroll
    for (int r = 0; r < 4; ++r) { m_i[r] = -1e30f; l_i[r] = 0.f; }

    const float kexp = 0.12751744f;  // log2(e)/sqrt(128)

    unsigned char* Pw = smem + VT_BYTES + KT_BYTES + wave * PW_BYTES;

    const int sc0 = threadIdx.x & 15;   // d-chunk for V staging
    const int spr = threadIdx.x >> 4;   // pair row for V staging

    const size_t kvstride = (size_t)(H_ * D_);  // 2048 floats per key row
    const float* kbase = k_g + ((size_t)b * KLEN * H_ + h) * D_;
    const float* vbase = v_g + ((size_t)b * KLEN * H_ + h) * D_;

    for (int kt = 0; kt < KLEN / BN; ++kt) {
        __syncthreads();   // prior iteration's LDS reads complete

        // ---- stage K tile: Kt[key][d], fp32 -> bf16, 4 chunks/thread
        #pragma unroll
        for (int i = 0; i < 4; ++i) {
            const int id   = threadIdx.x + 256 * i;
            const int row  = id >> 4;          // 0..63
            const int dcol = (id & 15) * 8;
            const float* kp = kbase + (size_t)(kt * BN + row) * kvstride + dcol;
            f32x8 kv = *(const f32x8*)kp;
            uint4 w;
            w.x = pk2(kv[0], kv[1]); w.y = pk2(kv[2], kv[3]);
            w.z = pk2(kv[4], kv[5]); w.w = pk2(kv[6], kv[7]);
            *(uint4*)(KtB + (row * 136 + dcol) * 2) = w;
        }

        // ---- stage V tile transposed+swizzled into Vt
        #pragma unroll
        for (int rr = 0; rr < 2; ++rr) {
            const int r0 = 2 * (spr + 16 * rr);            // even tile-local key
            const float* vp = vbase + (size_t)(kt * BN + r0) * kvstride + sc0 * 8;
            f32x8 va = *(const f32x8*)vp;
            f32x8 vb = *(const f32x8*)(vp + kvstride);
            const int g_hi = r0 >> 3;
            const int woff = (r0 & 7) * 2;                 // dword-aligned (r0 even)
            #pragma unroll
            for (int j = 0; j < 8; ++j) {
                const int d = sc0 * 8 + j;
                const int g = g_hi ^ ((d ^ (d >> 3)) & 7);
                *(u32a*)(VtB + d * 128 + g * 16 + woff) = pk2(va[j], vb[j]);
            }
        }
        __syncthreads();   // tiles visible

        // ---- S = Q K^T (16 x 64 per wave), K B-frags from LDS
        f32x4 s[4];
        #pragma unroll
        for (int nt = 0; nt < 4; ++nt) {
            s[nt] = (f32x4){0.f, 0.f, 0.f, 0.f};
            const u16* kfp = (const u16*)KtB + (nt * 16 + c) * 136 + quad * 8;
            #pragma unroll
            for (int dc = 0; dc < 4; ++dc) {
                bf16x8 kf = *(const bf16x8*)(kfp + dc * 32);
                s[nt] = __builtin_amdgcn_mfma_f32_16x16x32_bf16(qf[dc], kf, s[nt], 0, 0, 0);
            }
        }

        // ---- online softmax (C-layout: row = quad*4+r, col = c)
        #pragma unroll
        for (int r = 0; r < 4; ++r) {
            float v = fmaxf(fmaxf(s[0][r], s[1][r]), fmaxf(s[2][r], s[3][r]));
            v = fmaxf(v, __shfl_xor(v, 1));
            v = fmaxf(v, __shfl_xor(v, 2));
            v = fmaxf(v, __shfl_xor(v, 4));
            v = fmaxf(v, __shfl_xor(v, 8));
            const float mnew  = fmaxf(m_i[r], v);
            const float alpha = exp2f((m_i[r] - mnew) * kexp);
            m_i[r] = mnew;
            l_i[r] *= alpha;
            #pragma unroll
            for (int dt = 0; dt < 8; ++dt) acc_o[dt][r] *= alpha;
            float sum = 0.f;
            #pragma unroll
            for (int nt = 0; nt < 4; ++nt) {
                const float p = exp2f((s[nt][r] - mnew) * kexp);
                sum += p;
                *(u16a*)(Pw + ((quad * 4 + r) * 72 + nt * 16 + c) * 2) = f2bf(p);
            }
            float t = sum;
            t += __shfl_xor(t, 1);
            t += __shfl_xor(t, 2);
            t += __shfl_xor(t, 4);
            t += __shfl_xor(t, 8);
            l_i[r] += t;
        }

        __syncthreads();   // P stores drained before A-frag reads

        // ---- O += P V
        #pragma unroll
        for (int kc = 0; kc < 2; ++kc) {
            bf16x8 pf = *(const bf16x8*)(Pw + (c * 72 + kc * 32 + quad * 8) * 2);
            const int k0 = kc * 32 + quad * 8;
            #pragma unroll
            for (int dt = 0; dt < 8; ++dt) {
                const int d = dt * 16 + c;
                const int g = (k0 >> 3) ^ ((d ^ (d >> 3)) & 7);
                bf16x8 vf = *(const bf16x8*)(VtB + d * 128 + g * 16);
                acc_o[dt] = __builtin_amdgcn_mfma_f32_16x16x32_bf16(pf, vf, acc_o[dt], 0, 0, 0);
            }
        }
    }

    // ---- epilogue: O / l, fp32 store
    #pragma unroll
    for (int r = 0; r < 4; ++r) {
        const float inv = 1.f / l_i[r];
        const int qrow = q0 + quad * 4 + r;
        float* op = o_g + (size_t)(b * T_ + qrow) * (H_ * D_) + h * D_ + c;
        #pragma unroll
        for (int dt = 0; dt < 8; ++dt)
            op[dt * 16] = acc_o[dt][r] * inv;
    }
}

extern "C" void kernel_launch(void* const* d_in, const int* in_sizes, int n_in,
                              void* d_out, int out_size, void* d_ws, size_t ws_size,
                              hipStream_t stream) {
    const float* q = (const float*)d_in[0];
    const float* k = (const float*)d_in[1];
    const float* v = (const float*)d_in[2];
    float* o = (float*)d_out;
    // grid: (T/64 q-tiles) x (B*H) = 32 * 32 = 1024 blocks, 256 threads
    gqa_fa_kernel<<<dim3(1024), dim3(256), 0, stream>>>(q, k, v, o);
}